// Round 2
// baseline (110.862 us; speedup 1.0000x reference)
//
#include <hip/hip_runtime.h>

// DepthToSpace, BLOCK_SIZE=2
// in : x[B=16][C=256][H=128][W=128] f32   (C = (i*2+k)*64 + dd)
// out: y[B=16][d=64][2H=256][2W=256] f32
// out[b, dd, h*2+i, w*2+k] = x[b, (i*2+k)*64 + dd, h, w]
//
// Each thread produces 8 consecutive output floats (two float4 stores, 32B):
//   out cols W8*8 .. W8*8+7 -> (w0..w0+3) interleaved over k=0/1
// Reads one float4 from channel c0 = i*128+dd and one from c1 = c0+64
// (16B/lane, contiguous across lanes). Writes 32B/lane contiguous.

__global__ __launch_bounds__(256) void d2s_kernel(const float* __restrict__ x,
                                                  float* __restrict__ out,
                                                  int n8) {
    int t = blockIdx.x * blockDim.x + threadIdx.x;
    if (t >= n8) return;

    // t = ((b*64 + dd)*256 + H)*32 + W8        (W8 = output col / 8)
    int W8 = t & 31;
    int H  = (t >> 5) & 255;
    int dd = (t >> 13) & 63;
    int b  = t >> 19;

    int h  = H >> 1;
    int i  = H & 1;
    int w0 = W8 << 2;                 // 4 input w-values per thread

    int c0 = (i << 7) + dd;           // input channel for k=0; k=1 is c0+64
    // input flat offset: ((b*256 + c)*128 + h)*128 + w
    int base = (b << 22) + (c0 << 14) + (h << 7) + w0;

    float4 a = *reinterpret_cast<const float4*>(x + base);              // k=0
    float4 c = *reinterpret_cast<const float4*>(x + base + (64 << 14)); // k=1

    float4 o0, o1;
    o0.x = a.x; o0.y = c.x; o0.z = a.y; o0.w = c.y;
    o1.x = a.z; o1.y = c.z; o1.z = a.w; o1.w = c.w;

    float4* outv = reinterpret_cast<float4*>(out);
    outv[2 * t]     = o0;
    outv[2 * t + 1] = o1;
}

extern "C" void kernel_launch(void* const* d_in, const int* in_sizes, int n_in,
                              void* d_out, int out_size, void* d_ws, size_t ws_size,
                              hipStream_t stream) {
    const float* x = (const float*)d_in[0];
    float* out = (float*)d_out;
    int n8 = out_size / 8;                 // 8,388,608 threads
    int block = 256;
    int grid = (n8 + block - 1) / block;   // 32768 blocks
    d2s_kernel<<<grid, block, 0, stream>>>(x, out, n8);
}